// Round 9
// baseline (683.695 us; speedup 1.0000x reference)
//
#include <hip/hip_runtime.h>
#include <math.h>

#define NU 50000
#define NI 50000
#define NN 50000
#define DD 64
#define HHID 128
#define EE 500000
#define NEG_SLOPE 0.01f
#define NBKT 98            // coarse buckets of 512 nodes (dst>>9)
#define CAP 6144           // capacity per (graph,bucket) coarse region
#define TILE 4096
#define TPG 123            // tiles per graph = ceil(500000/4096)
#define NBG 1563           // gc blocks per graph (32 nodes each, 50016 >= 50000)
#define GCB (4 * NBG)      // total gc blocks
#define GATB 6250          // gat blocks (32 nodes each, 200000 exactly)

typedef _Float16 half_t;
typedef _Float16 half8 __attribute__((ext_vector_type(8)));
typedef float f32x4 __attribute__((ext_vector_type(4)));
union H4 { uint2 u; half_t h[4]; };
union H8 { uint4 u; half_t h[8]; };

struct Ptr4c { const float* p[4]; };
struct Ptr4m { float*       p[4]; };
struct EdgeArgs { const int* src[8]; const int* dst[8]; };
struct GatArgs { const float* el[4]; const float* er[4]; const half_t* fsrc[4]; half_t* zout[4]; };
struct GcArgs  { const half_t* feat[4]; half_t* hout[4]; };
struct SemArgs { const half_t* z[4]; const float* W1[4]; const float* b1[4]; const float* w2[4]; };

// ---------------- fused: fp32 feat -> fp16 table + 4 per-node dots; wave = 4 nodes x 16 lanes
__global__ void dot4_kernel(const float* __restrict__ feat, Ptr4c vecs, Ptr4m outs,
                            half_t* __restrict__ fb16, int n) {
    int gid = blockIdx.x * blockDim.x + threadIdx.x;
    int w = gid >> 6;
    int lane = threadIdx.x & 63;
    int sub = lane >> 4, r = lane & 15;
    int node = w * 4 + sub;
    if (node >= n) return;
    float4 f = *(const float4*)(feat + (size_t)node * DD + r * 4);
    H4 o16;
    o16.h[0] = (half_t)f.x; o16.h[1] = (half_t)f.y; o16.h[2] = (half_t)f.z; o16.h[3] = (half_t)f.w;
    *(uint2*)(fb16 + (size_t)node * DD + r * 4) = o16.u;
#pragma unroll
    for (int j = 0; j < 4; j++) {
        float4 vv = *(const float4*)(vecs.p[j] + r * 4);
        float val = f.x * vv.x + f.y * vv.y + f.z * vv.z + f.w * vv.w;
        val += __shfl_down(val, 8);
        val += __shfl_down(val, 4);
        val += __shfl_down(val, 2);
        val += __shfl_down(val, 1);
        if (r == 0) outs.p[j][node] = val;
    }
}

// ---------------- W_gc -> fragment-ordered fp16: W16[((g*8 + nt*2+kh)*64 + lane)*8 + j]
__global__ void prepw_kernel(const float* __restrict__ W_gc, half_t* __restrict__ W16) {
    int g = blockIdx.x;
    int lane = threadIdx.x;
    int cl = lane & 15, quad = lane >> 4;
#pragma unroll
    for (int nt = 0; nt < 4; nt++) {
#pragma unroll
        for (int kh = 0; kh < 2; kh++) {
            H8 o;
#pragma unroll
            for (int j = 0; j < 8; j++) {
                int k = kh * 32 + quad * 8 + j;
                int n = nt * 16 + cl;
                o.h[j] = (half_t)W_gc[g * 4096 + k * 64 + n];
            }
            *(uint4*)(W16 + ((size_t)(g * 8 + nt * 2 + kh) * 64 + lane) * 8) = o.u;
        }
    }
}

// ---------------- pass 1: LDS counting-sort partition by dst>>9; packed record src|(dst&511)<<16
__global__ __launch_bounds__(256) void part1_kernel(EdgeArgs a, int* __restrict__ ccnt,
                                                    int* __restrict__ coarse,
                                                    int* __restrict__ deg_src) {
    __shared__ int bc_cnt[128], bc_scan[128], bc_start[128], bc_cur[128], bc_gbase[128];
    __shared__ int stage[TILE];
    __shared__ unsigned char sbkt[TILE];
    int t = threadIdx.x;
    int g = blockIdx.x / TPG;
    int tile = blockIdx.x % TPG;
    int e0 = tile * TILE;
    int tile_n = min(TILE, EE - e0);
    const int* gs = a.src[g];
    const int* gd = a.dst[g];
    if (t < 128) bc_cnt[t] = 0;
    __syncthreads();
    int pw[16]; int pb[16];
#pragma unroll
    for (int i = 0; i < 16; i++) {
        int pos = i * 256 + t;
        pb[i] = -1;
        if (pos < tile_n) {
            int e = e0 + pos;
            int s = gs[e], d = gd[e];
            pw[i] = s | ((d & 511) << 16);
            pb[i] = d >> 9;
            atomicAdd(&bc_cnt[pb[i]], 1);
            if (g >= 4) atomicAdd(&deg_src[(g - 4) * NN + s], 1);
        }
    }
    __syncthreads();
    if (t < 128) bc_scan[t] = bc_cnt[t];
    __syncthreads();
    for (int off = 1; off < 128; off <<= 1) {
        int v = 0;
        if (t < 128 && t >= off) v = bc_scan[t - off];
        __syncthreads();
        if (t < 128) bc_scan[t] += v;
        __syncthreads();
    }
    if (t < 128) {
        int st = bc_scan[t] - bc_cnt[t];
        bc_start[t] = st;
        bc_cur[t] = st;
        bc_gbase[t] = (t < NBKT && bc_cnt[t] > 0) ? atomicAdd(&ccnt[g * NBKT + t], bc_cnt[t]) : 0;
    }
    __syncthreads();
#pragma unroll
    for (int i = 0; i < 16; i++) {
        if (pb[i] >= 0) {
            int slot = atomicAdd(&bc_cur[pb[i]], 1);
            stage[slot] = pw[i];
            sbkt[slot] = (unsigned char)pb[i];
        }
    }
    __syncthreads();
    for (int j = t; j < tile_n; j += 256) {
        int b = sbkt[j];
        int p = stage[j];
        int pos = bc_gbase[b] + (j - bc_start[b]);
        if (pos < CAP) coarse[(size_t)(g * NBKT + b) * CAP + pos] = p;
    }
}

// ---------------- per-graph exclusive scan of coarse bucket counts
__global__ void scanb_kernel(const int* __restrict__ ccnt, int* __restrict__ bktbase) {
    __shared__ int s[128];
    int g = blockIdx.x, t = threadIdx.x;
    int orig = (t < NBKT) ? min(ccnt[g * NBKT + t], CAP) : 0;
    s[t] = orig;
    __syncthreads();
    for (int off = 1; off < 128; off <<= 1) {
        int v = (t >= off) ? s[t - off] : 0;
        __syncthreads();
        s[t] += v;
        __syncthreads();
    }
    if (t < NBKT) bktbase[g * NBKT + t] = s[t] - orig;
}

// ---------------- pass 2: per (graph,bucket) counting sort -> final CSR + row_start + deg + ni
__global__ __launch_bounds__(256) void part2_kernel(const int* __restrict__ ccnt,
                                                    const int* __restrict__ bktbase,
                                                    const int* __restrict__ coarse,
                                                    int* __restrict__ bucket,
                                                    int* __restrict__ row_start,
                                                    int* __restrict__ dega,
                                                    float* __restrict__ nirm) {
    __shared__ int cnt5[512], off5[512], s2[256];
    __shared__ int spairs[CAP];
    __shared__ int ordered[CAP];
    int t = threadIdx.x;
    int g = blockIdx.x / NBKT;
    int b = blockIdx.x % NBKT;
    int n = min(ccnt[g * NBKT + b], CAP);
    int base = bktbase[g * NBKT + b];
    int node0 = b << 9;
    cnt5[t] = 0; cnt5[t + 256] = 0;
    __syncthreads();
    const int* pairs = coarse + (size_t)(g * NBKT + b) * CAP;
    for (int i = t; i < n; i += 256) {
        int p = pairs[i];
        spairs[i] = p;
        atomicAdd(&cnt5[p >> 16], 1);
    }
    __syncthreads();
    int pairsum = cnt5[2 * t] + cnt5[2 * t + 1];
    s2[t] = pairsum;
    __syncthreads();
    for (int off = 1; off < 256; off <<= 1) {
        int v = (t >= off) ? s2[t - off] : 0;
        __syncthreads();
        s2[t] += v;
        __syncthreads();
    }
    int ex = s2[t] - pairsum;
    off5[2 * t] = ex;
    off5[2 * t + 1] = ex + cnt5[2 * t];
    __syncthreads();
#pragma unroll
    for (int k = 0; k < 2; k++) {
        int j = 2 * t + k;
        int v = node0 + j;
        if (v < NN) {
            row_start[g * NN + v] = base + off5[j];
            int d = cnt5[j];
            dega[g * NN + v] = d;
            if (g >= 4) nirm[(g - 4) * NN + v] = (d > 0) ? rsqrtf((float)d) : 1.0f;
        }
    }
    __syncthreads();
    for (int i = t; i < n; i += 256) {
        int p = spairs[i];
        int slot = atomicAdd(&off5[p >> 16], 1);
        ordered[slot] = p & 0xFFFF;
    }
    __syncthreads();
    for (int i = t; i < n; i += 256) bucket[(size_t)g * EE + base + i] = ordered[i];
}

__global__ void normno_kernel(const int* __restrict__ deg_src, float* __restrict__ no) {
    int i = blockIdx.x * blockDim.x + threadIdx.x;
    if (i >= 4 * NN) return;
    int d = deg_src[i];
    no[i] = (d > 0) ? rsqrtf((float)d) : 1.0f;
}

// ---------------- fused gather: blocks [0,GCB) = GC (32 nodes, 2/wave, MFMA transform),
// blocks [GCB, GCB+GATB) = GAT (32 nodes, 2/wave, inline softmax)
__global__ __launch_bounds__(1024) void gather_kernel(GatArgs ga, GcArgs gc,
                                                      const half_t* __restrict__ W16,
                                                      const float* __restrict__ b_gc,
                                                      const float* __restrict__ NO,
                                                      const float* __restrict__ NIrm,
                                                      const int* __restrict__ dega,
                                                      const int* __restrict__ row_start,
                                                      const int* __restrict__ bucket) {
    __shared__ half_t srow[2][16][72];       // two 16-node tiles, padded rows
    int t = threadIdx.x;
    int wv = t >> 6, lane = t & 63;
    int q = lane >> 3, r = lane & 7;

    if (blockIdx.x < GCB) {
        // ================= GC =================
        int g = blockIdx.x / NBG;
        int nb = blockIdx.x % NBG;
        const int* bk  = bucket + (size_t)(4 + g) * EE;
        const int* deg = dega + (4 + g) * NN;
        const int* row = row_start + (4 + g) * NN;
        const float* no = NO + g * NN;
        const half_t* feat = gc.feat[g];
        int v0 = nb * 32 + wv, v1 = v0 + 16;
        int dg0 = (v0 < NN) ? deg[v0] : 0;
        int dg1 = (v1 < NN) ? deg[v1] : 0;
        int st0 = (v0 < NN) ? row[v0] : 0;
        int st1 = (v1 < NN) ? row[v1] : 0;
        float acc0[8], acc1[8];
#pragma unroll
        for (int i = 0; i < 8; i++) { acc0[i] = 0.f; acc1[i] = 0.f; }
        int dmax = max(dg0, dg1);
        for (int base = 0; base < dmax; base += 16) {
            int eA = base + q, eB = base + 8 + q;
            bool a0 = eA < dg0, b0 = eB < dg0, a1 = eA < dg1, b1 = eB < dg1;
            int sA0 = a0 ? bk[st0 + eA] : 0;
            int sB0 = b0 ? bk[st0 + eB] : 0;
            int sA1 = a1 ? bk[st1 + eA] : 0;
            int sB1 = b1 ? bk[st1 + eB] : 0;
            float nA0 = a0 ? no[sA0] : 0.f;
            float nB0 = b0 ? no[sB0] : 0.f;
            float nA1 = a1 ? no[sA1] : 0.f;
            float nB1 = b1 ? no[sB1] : 0.f;
            if (a0) {
                H8 rw; rw.u = *(const uint4*)(feat + (size_t)sA0 * DD + r * 8);
#pragma unroll
                for (int i = 0; i < 8; i++) acc0[i] += nA0 * (float)rw.h[i];
            }
            if (b0) {
                H8 rw; rw.u = *(const uint4*)(feat + (size_t)sB0 * DD + r * 8);
#pragma unroll
                for (int i = 0; i < 8; i++) acc0[i] += nB0 * (float)rw.h[i];
            }
            if (a1) {
                H8 rw; rw.u = *(const uint4*)(feat + (size_t)sA1 * DD + r * 8);
#pragma unroll
                for (int i = 0; i < 8; i++) acc1[i] += nA1 * (float)rw.h[i];
            }
            if (b1) {
                H8 rw; rw.u = *(const uint4*)(feat + (size_t)sB1 * DD + r * 8);
#pragma unroll
                for (int i = 0; i < 8; i++) acc1[i] += nB1 * (float)rw.h[i];
            }
        }
#pragma unroll
        for (int off = 8; off < 64; off <<= 1) {
#pragma unroll
            for (int i = 0; i < 8; i++) {
                acc0[i] += __shfl_down(acc0[i], off);
                acc1[i] += __shfl_down(acc1[i], off);
            }
        }
        if (lane < 8) {
            float ni0 = (v0 < NN) ? NIrm[g * NN + v0] : 0.f;
            float ni1 = (v1 < NN) ? NIrm[g * NN + v1] : 0.f;
            H8 o0, o1;
#pragma unroll
            for (int i = 0; i < 8; i++) {
                o0.h[i] = (half_t)(acc0[i] * ni0);
                o1.h[i] = (half_t)(acc1[i] * ni1);
            }
            *(uint4*)(&srow[0][wv][r * 8]) = o0.u;
            *(uint4*)(&srow[1][wv][r * 8]) = o1.u;
        }
        __syncthreads();
        if (wv < 2) {
            int cl = lane & 15, quad = lane >> 4;
            half8 A0 = *(const half8*)(&srow[wv][cl][quad * 8]);
            half8 A1 = *(const half8*)(&srow[wv][cl][32 + quad * 8]);
            const half_t* wbase = W16 + (size_t)g * 8 * 64 * 8;
            half_t* hout = gc.hout[g];
            int nbase = nb * 32 + wv * 16;
#pragma unroll
            for (int nt = 0; nt < 4; nt++) {
                float bb = b_gc[g * 64 + nt * 16 + cl];
                f32x4 c = {bb, bb, bb, bb};
                half8 B0 = *(const half8*)(wbase + ((size_t)(nt * 2 + 0) * 64 + lane) * 8);
                half8 B1 = *(const half8*)(wbase + ((size_t)(nt * 2 + 1) * 64 + lane) * 8);
                c = __builtin_amdgcn_mfma_f32_16x16x32_f16(A0, B0, c, 0, 0, 0);
                c = __builtin_amdgcn_mfma_f32_16x16x32_f16(A1, B1, c, 0, 0, 0);
#pragma unroll
                for (int r_ = 0; r_ < 4; r_++) {
                    int node = nbase + quad * 4 + r_;
                    if (node < NN) {
                        float x = c[r_];
                        x = (x > 0.f) ? x : expm1f(x);
                        hout[(size_t)node * 128 + nt * 16 + cl] = (half_t)x;
                    }
                }
            }
        }
    } else {
        // ================= GAT =================
        int blk = blockIdx.x - GCB;
        int idx0 = blk * 32 + wv, idx1 = idx0 + 16;
        int g0 = idx0 / NN, v0 = idx0 % NN;
        int g1 = idx1 / NN, v1 = idx1 % NN;
        int dg0 = dega[g0 * NN + v0];
        int dg1 = dega[g1 * NN + v1];
        int st0 = row_start[g0 * NN + v0];
        int st1 = row_start[g1 * NN + v1];
        const int* bk0 = bucket + (size_t)g0 * EE;
        const int* bk1 = bucket + (size_t)g1 * EE;
        const float* el0 = ga.el[g0];
        const float* el1 = ga.el[g1];
        const half_t* fs0 = ga.fsrc[g0];
        const half_t* fs1 = ga.fsrc[g1];
        float er0 = ga.er[g0][v0];
        float er1 = ga.er[g1][v1];
        float acc0[8], acc1[8];
#pragma unroll
        for (int i = 0; i < 8; i++) { acc0[i] = 0.f; acc1[i] = 0.f; }
        float sl0 = 0.f, sl1 = 0.f;
        int dmax = max(dg0, dg1);
        for (int base = 0; base < dmax; base += 16) {
            int eA = base + q, eB = base + 8 + q;
            bool a0 = eA < dg0, b0 = eB < dg0, a1 = eA < dg1, b1 = eB < dg1;
            int sA0 = a0 ? bk0[st0 + eA] : 0;
            int sB0 = b0 ? bk0[st0 + eB] : 0;
            int sA1 = a1 ? bk1[st1 + eA] : 0;
            int sB1 = b1 ? bk1[st1 + eB] : 0;
            float wA0 = 0.f, wB0 = 0.f, wA1 = 0.f, wB1 = 0.f;
            if (a0) { float e = el0[sA0] + er0; e = (e >= 0.f) ? e : NEG_SLOPE * e; wA0 = expf(e); }
            if (b0) { float e = el0[sB0] + er0; e = (e >= 0.f) ? e : NEG_SLOPE * e; wB0 = expf(e); }
            if (a1) { float e = el1[sA1] + er1; e = (e >= 0.f) ? e : NEG_SLOPE * e; wA1 = expf(e); }
            if (b1) { float e = el1[sB1] + er1; e = (e >= 0.f) ? e : NEG_SLOPE * e; wB1 = expf(e); }
            sl0 += wA0 + wB0;
            sl1 += wA1 + wB1;
            if (a0) {
                H8 rw; rw.u = *(const uint4*)(fs0 + (size_t)sA0 * DD + r * 8);
#pragma unroll
                for (int i = 0; i < 8; i++) acc0[i] += wA0 * (float)rw.h[i];
            }
            if (b0) {
                H8 rw; rw.u = *(const uint4*)(fs0 + (size_t)sB0 * DD + r * 8);
#pragma unroll
                for (int i = 0; i < 8; i++) acc0[i] += wB0 * (float)rw.h[i];
            }
            if (a1) {
                H8 rw; rw.u = *(const uint4*)(fs1 + (size_t)sA1 * DD + r * 8);
#pragma unroll
                for (int i = 0; i < 8; i++) acc1[i] += wA1 * (float)rw.h[i];
            }
            if (b1) {
                H8 rw; rw.u = *(const uint4*)(fs1 + (size_t)sB1 * DD + r * 8);
#pragma unroll
                for (int i = 0; i < 8; i++) acc1[i] += wB1 * (float)rw.h[i];
            }
        }
#pragma unroll
        for (int off = 8; off < 64; off <<= 1) {
#pragma unroll
            for (int i = 0; i < 8; i++) {
                acc0[i] += __shfl_down(acc0[i], off);
                acc1[i] += __shfl_down(acc1[i], off);
            }
            sl0 += __shfl_down(sl0, off);
            sl1 += __shfl_down(sl1, off);
        }
        if (lane < 8) {
            float inv0 = (dg0 > 0) ? (1.0f / sl0) : 0.f;
            float inv1 = (dg1 > 0) ? (1.0f / sl1) : 0.f;
            H8 o0, o1;
#pragma unroll
            for (int i = 0; i < 8; i++) {
                float x0 = acc0[i] * inv0;
                x0 = (x0 > 0.f) ? x0 : expm1f(x0);
                o0.h[i] = (half_t)x0;
                float x1 = acc1[i] * inv1;
                x1 = (x1 > 0.f) ? x1 : expm1f(x1);
                o1.h[i] = (half_t)x1;
            }
            *(uint4*)(ga.zout[g0] + (size_t)v0 * 128 + r * 8) = o0.u;
            *(uint4*)(ga.zout[g1] + (size_t)v1 * 128 + r * 8) = o1.u;
        }
    }
}

// ---------------- semantic attention via MFMA (validated layout)
__global__ __launch_bounds__(256) void sem_att_kernel(SemArgs sa, float* __restrict__ wsum) {
    int inst = blockIdx.x >> 8;
    int blk  = blockIdx.x & 255;
    int t = threadIdx.x;
    int wv = t >> 6, lane = t & 63;
    int quad = lane >> 4, cl = lane & 15;
    const half_t* z = sa.z[inst];
    const float* W1 = sa.W1[inst];
    half8 Bf[8][2];
    float b1v[8], w2v[8];
#pragma unroll
    for (int nt = 0; nt < 8; nt++) {
        int n = nt * 16 + cl;
#pragma unroll
        for (int kh = 0; kh < 2; kh++) {
#pragma unroll
            for (int j = 0; j < 8; j++) {
                int k = kh * 32 + quad * 8 + j;
                Bf[nt][kh][j] = (half_t)W1[k * HHID + n];
            }
        }
        b1v[nt] = sa.b1[inst][n];
        w2v[nt] = sa.w2[inst][n];
    }
    float local0 = 0.f, local1 = 0.f;
    int wave_id = blk * 4 + wv;
    for (int tile = wave_id; tile < 6250; tile += 1024) {
        int m = (tile >= 3125) ? 1 : 0;
        int node = (tile - m * 3125) * 16 + cl;
        const half_t* zr = z + (size_t)node * 128 + m * 64 + quad * 8;
        half8 A0 = *(const half8*)(zr);
        half8 A1 = *(const half8*)(zr + 32);
        float sumv = 0.f;
#pragma unroll
        for (int nt = 0; nt < 8; nt++) {
            f32x4 c = {0.f, 0.f, 0.f, 0.f};
            c = __builtin_amdgcn_mfma_f32_16x16x32_f16(A0, Bf[nt][0], c, 0, 0, 0);
            c = __builtin_amdgcn_mfma_f32_16x16x32_f16(A1, Bf[nt][1], c, 0, 0, 0);
#pragma unroll
            for (int r = 0; r < 4; r++) sumv += tanhf(c[r] + b1v[nt]) * w2v[nt];
        }
#pragma unroll
        for (int off = 32; off > 0; off >>= 1) sumv += __shfl_down(sumv, off);
        if (lane == 0) { if (m == 0) local0 += sumv; else local1 += sumv; }
    }
    if (lane == 0) {
        if (local0 != 0.f) atomicAdd(&wsum[inst * 2 + 0], local0);
        if (local1 != 0.f) atomicAdd(&wsum[inst * 2 + 1], local1);
    }
}

// ---------------- final combine: thread = 4 consecutive output cols
__global__ void combine_kernel(const half_t* __restrict__ ZU, const half_t* __restrict__ ZI,
                               const half_t* __restrict__ HU, const half_t* __restrict__ HI,
                               const float* __restrict__ wsum, float* __restrict__ out) {
    int gid = blockIdx.x * blockDim.x + threadIdx.x;
    if (gid >= (NU + NI) * 16) return;
    int node = gid >> 4;
    int c4 = (gid & 15) * 4;
    const half_t* zb; const half_t* hb;
    float wr0, wr1, wh0, wh1;
    int idx;
    if (node < NU) {
        zb = ZU; hb = HU; idx = node;
        wr0 = wsum[0]; wr1 = wsum[1]; wh0 = wsum[4]; wh1 = wsum[5];
    } else {
        zb = ZI; hb = HI; idx = node - NU;
        wr0 = wsum[2]; wr1 = wsum[3]; wh0 = wsum[6]; wh1 = wsum[7];
    }
    const float inv_n = 1.0f / 50000.0f;
    wr0 *= inv_n; wr1 *= inv_n; wh0 *= inv_n; wh1 *= inv_n;
    float m = fmaxf(wr0, wr1);
    float e0 = expf(wr0 - m), e1 = expf(wr1 - m);
    float br0 = e0 / (e0 + e1), br1 = e1 / (e0 + e1);
    m = fmaxf(wh0, wh1);
    e0 = expf(wh0 - m); e1 = expf(wh1 - m);
    float bh0 = e0 / (e0 + e1), bh1 = e1 / (e0 + e1);
    H4 z0, z1, h0, h1;
    z0.u = *(const uint2*)(zb + (size_t)idx * 128 + c4);
    z1.u = *(const uint2*)(zb + (size_t)idx * 128 + 64 + c4);
    h0.u = *(const uint2*)(hb + (size_t)idx * 128 + c4);
    h1.u = *(const uint2*)(hb + (size_t)idx * 128 + 64 + c4);
    float4 o;
    o.x = (float)z0.h[0] * br0 + (float)z1.h[0] * br1 + (float)h0.h[0] * bh0 + (float)h1.h[0] * bh1;
    o.y = (float)z0.h[1] * br0 + (float)z1.h[1] * br1 + (float)h0.h[1] * bh0 + (float)h1.h[1] * bh1;
    o.z = (float)z0.h[2] * br0 + (float)z1.h[2] * br1 + (float)h0.h[2] * bh0 + (float)h1.h[2] * bh1;
    o.w = (float)z0.h[3] * br0 + (float)z1.h[3] * br1 + (float)h0.h[3] * bh0 + (float)h1.h[3] * bh1;
    *(float4*)(out + (size_t)node * 64 + c4) = o;
}

extern "C" void kernel_launch(void* const* d_in, const int* in_sizes, int n_in,
                              void* d_out, int out_size, void* d_ws, size_t ws_size,
                              hipStream_t stream) {
    const float* feat_user = (const float*)d_in[0];
    const float* feat_item = (const float*)d_in[1];
    const float* attn_l    = (const float*)d_in[2];
    const float* attn_r    = (const float*)d_in[3];
    const float* W_gc      = (const float*)d_in[4];
    const float* b_gc      = (const float*)d_in[5];
    const float* sa_rel_W1 = (const float*)d_in[6];
    const float* sa_rel_b1 = (const float*)d_in[7];
    const float* sa_rel_w2 = (const float*)d_in[8];
    const float* sa_u_W1   = (const float*)d_in[9];
    const float* sa_u_b1   = (const float*)d_in[10];
    const float* sa_u_w2   = (const float*)d_in[11];
    const float* sa_i_W1   = (const float*)d_in[12];
    const float* sa_i_b1   = (const float*)d_in[13];
    const float* sa_i_w2   = (const float*)d_in[14];
    const int* rel_u_src = (const int*)d_in[15];
    const int* rel_u_dst = (const int*)d_in[16];
    const int* rel_i_src = (const int*)d_in[17];
    const int* rel_i_dst = (const int*)d_in[18];
    const int* mp_u_src  = (const int*)d_in[19];
    const int* mp_u_dst  = (const int*)d_in[20];
    const int* mp_i_src  = (const int*)d_in[21];
    const int* mp_i_dst  = (const int*)d_in[22];

    // ---- workspace layout ----
    half_t* ZU   = (half_t*)d_ws;             // NN*128 fp16
    half_t* ZI   = ZU + NN * 128;
    half_t* HU   = ZI + NN * 128;
    half_t* HI   = HU + NN * 128;
    half_t* FBU  = HI + NN * 128;             // fp16 feat_user, NN*64
    half_t* FBI  = FBU + NN * 64;             // fp16 feat_item, NN*64
    float*  DI   = (float*)(FBI + NN * 64);   // 4*NN
    float*  DU   = DI + 4 * NN;               // 4*NN
    float*  NO   = DU + 4 * NN;               // 4*NN
    float*  NIrm = NO + 4 * NN;               // 4*NN
    int*    ROW  = (int*)(NIrm + 4 * NN);     // 8*NN
    int*    DEGA = ROW + 8 * NN;              // 8*NN
    int*    BUCKET = DEGA + 8 * NN;           // 8*EE
    int*    BKTBASE = BUCKET + 8 * EE;        // 8*128
    int*    CCNT = BKTBASE + 8 * 128;         // 8*128  -- zeroed
    int*    DEG_SRC = CCNT + 8 * 128;         // 4*NN   -- zeroed
    float*  WSUM = (float*)(DEG_SRC + 4 * NN);// 8      -- zeroed
    half_t* W16  = (half_t*)(WSUM + 8);       // 4*4096 fp16 fragment-ordered W
    int*    COARSE = (int*)d_ws;              // 8*98*CAP ints, aliases ZU..; dead before gathers

    hipMemsetAsync(CCNT, 0, (size_t)(8 * 128 + 4 * NN) * sizeof(int) + 8 * sizeof(float), stream);

    // ---- W fragment prep + fused fp16-cvt + dots ----
    prepw_kernel<<<4, 64, 0, stream>>>(W_gc, W16);
    Ptr4c vi = {{ attn_l + 0 * DD, attn_l + 1 * DD, attn_r + 2 * DD, attn_r + 3 * DD }};
    Ptr4m oi = {{ DI, DI + NI, DI + 2 * NI, DI + 3 * NI }};
    Ptr4c vu = {{ attn_l + 2 * DD, attn_l + 3 * DD, attn_r + 0 * DD, attn_r + 1 * DD }};
    Ptr4m ou = {{ DU, DU + NU, DU + 2 * NU, DU + 3 * NU }};
    dot4_kernel<<<(NN / 4 * 64) / 256, 256, 0, stream>>>(feat_item, vi, oi, FBI, NI);
    dot4_kernel<<<(NN / 4 * 64) / 256, 256, 0, stream>>>(feat_user, vu, ou, FBU, NU);

    // ---- CSR build ----
    EdgeArgs ea;
    ea.src[0] = rel_u_src;      ea.dst[0] = rel_u_dst;
    ea.src[1] = rel_u_src + EE; ea.dst[1] = rel_u_dst + EE;
    ea.src[2] = rel_i_src;      ea.dst[2] = rel_i_dst;
    ea.src[3] = rel_i_src + EE; ea.dst[3] = rel_i_dst + EE;
    ea.src[4] = mp_u_src;       ea.dst[4] = mp_u_dst;
    ea.src[5] = mp_u_src + EE;  ea.dst[5] = mp_u_dst + EE;
    ea.src[6] = mp_i_src;       ea.dst[6] = mp_i_dst;
    ea.src[7] = mp_i_src + EE;  ea.dst[7] = mp_i_dst + EE;

    part1_kernel<<<8 * TPG, 256, 0, stream>>>(ea, CCNT, COARSE, DEG_SRC);
    scanb_kernel<<<8, 128, 0, stream>>>(CCNT, BKTBASE);
    part2_kernel<<<8 * NBKT, 256, 0, stream>>>(CCNT, BKTBASE, COARSE, BUCKET, ROW, DEGA, NIrm);
    normno_kernel<<<(4 * NN + 255) / 256, 256, 0, stream>>>(DEG_SRC, NO);

    // ---- fused GAT + GC gather ----
    GatArgs ga;
    ga.el[0] = DI;          ga.er[0] = DU + 2 * NU; ga.fsrc[0] = FBI; ga.zout[0] = ZU;
    ga.el[1] = DI + NI;     ga.er[1] = DU + 3 * NU; ga.fsrc[1] = FBI; ga.zout[1] = ZU + 64;
    ga.el[2] = DU;          ga.er[2] = DI + 2 * NI; ga.fsrc[2] = FBU; ga.zout[2] = ZI;
    ga.el[3] = DU + NU;     ga.er[3] = DI + 3 * NI; ga.fsrc[3] = FBU; ga.zout[3] = ZI + 64;
    GcArgs gc;
    gc.feat[0] = FBU; gc.hout[0] = HU;
    gc.feat[1] = FBU; gc.hout[1] = HU + 64;
    gc.feat[2] = FBI; gc.hout[2] = HI;
    gc.feat[3] = FBI; gc.hout[3] = HI + 64;
    gather_kernel<<<GCB + GATB, 1024, 0, stream>>>(ga, gc, W16, b_gc, NO, NIrm, DEGA, ROW, BUCKET);

    // ---- semantic attention (single launch, 4 instances, MFMA) ----
    SemArgs sa;
    sa.z[0] = ZU; sa.W1[0] = sa_rel_W1; sa.b1[0] = sa_rel_b1; sa.w2[0] = sa_rel_w2;
    sa.z[1] = ZI; sa.W1[1] = sa_rel_W1; sa.b1[1] = sa_rel_b1; sa.w2[1] = sa_rel_w2;
    sa.z[2] = HU; sa.W1[2] = sa_u_W1;   sa.b1[2] = sa_u_b1;   sa.w2[2] = sa_u_w2;
    sa.z[3] = HI; sa.W1[3] = sa_i_W1;   sa.b1[3] = sa_i_b1;   sa.w2[3] = sa_i_w2;
    sem_att_kernel<<<4 * 256, 256, 0, stream>>>(sa, WSUM);

    // ---- combine ----
    combine_kernel<<<((NU + NI) * 16 + 255) / 256, 256, 0, stream>>>(ZU, ZI, HU, HI, WSUM, (float*)d_out);
}

// Round 10
// 580.767 us; speedup vs baseline: 1.1772x; 1.1772x over previous
//
#include <hip/hip_runtime.h>
#include <math.h>

#define NU 50000
#define NI 50000
#define NN 50000
#define DD 64
#define HHID 128
#define EE 500000
#define NEG_SLOPE 0.01f
#define NBKT 98            // coarse buckets of 512 nodes (dst>>9)
#define CAP 6144           // capacity per (graph,bucket) coarse region
#define TILE 4096
#define TPG 123            // tiles per graph = ceil(500000/4096)

typedef _Float16 half_t;
typedef _Float16 half8 __attribute__((ext_vector_type(8)));
typedef float f32x4 __attribute__((ext_vector_type(4)));
union H4 { uint2 u; half_t h[4]; };
union H8 { uint4 u; half_t h[8]; };
union HS { half8 h; int i[4]; uint4 u; };

struct Ptr4c { const float* p[4]; };
struct Ptr4m { float*       p[4]; };
struct EdgeArgs { const int* src[8]; const int* dst[8]; };
struct GatArgs { const float* el[4]; const float* er[4]; const half_t* fsrc[4]; half_t* zout[4]; };
struct GcArgs  { const half_t* feat[4]; half_t* hout[4]; };
struct SemArgs { const half_t* z[4]; const float* W1[4]; const float* b1[4]; const float* w2[4]; };

// ---------------- fused: fp32 feat -> fp16 table + 4 per-node dots; wave = 4 nodes x 16 lanes
__global__ void dot4_kernel(const float* __restrict__ feat, Ptr4c vecs, Ptr4m outs,
                            half_t* __restrict__ fb16, int n) {
    int gid = blockIdx.x * blockDim.x + threadIdx.x;
    int w = gid >> 6;
    int lane = threadIdx.x & 63;
    int sub = lane >> 4, r = lane & 15;
    int node = w * 4 + sub;
    if (node >= n) return;
    float4 f = *(const float4*)(feat + (size_t)node * DD + r * 4);
    H4 o16;
    o16.h[0] = (half_t)f.x; o16.h[1] = (half_t)f.y; o16.h[2] = (half_t)f.z; o16.h[3] = (half_t)f.w;
    *(uint2*)(fb16 + (size_t)node * DD + r * 4) = o16.u;
#pragma unroll
    for (int j = 0; j < 4; j++) {
        float4 vv = *(const float4*)(vecs.p[j] + r * 4);
        float val = f.x * vv.x + f.y * vv.y + f.z * vv.z + f.w * vv.w;
        val += __shfl_down(val, 8);
        val += __shfl_down(val, 4);
        val += __shfl_down(val, 2);
        val += __shfl_down(val, 1);
        if (r == 0) outs.p[j][node] = val;
    }
}

// ---------------- W_gc -> fragment-ordered fp16: W16[((g*8 + nt*2+kh)*64 + lane)*8 + j]
__global__ void prepw_kernel(const float* __restrict__ W_gc, half_t* __restrict__ W16) {
    int g = blockIdx.x;
    int lane = threadIdx.x;
    int cl = lane & 15, quad = lane >> 4;
#pragma unroll
    for (int nt = 0; nt < 4; nt++) {
#pragma unroll
        for (int kh = 0; kh < 2; kh++) {
            H8 o;
#pragma unroll
            for (int j = 0; j < 8; j++) {
                int k = kh * 32 + quad * 8 + j;
                int n = nt * 16 + cl;
                o.h[j] = (half_t)W_gc[g * 4096 + k * 64 + n];
            }
            *(uint4*)(W16 + ((size_t)(g * 8 + nt * 2 + kh) * 64 + lane) * 8) = o.u;
        }
    }
}

// ---------------- pass 1: LDS counting-sort partition by dst>>9; packed record src|(dst&511)<<16
__global__ __launch_bounds__(256) void part1_kernel(EdgeArgs a, int* __restrict__ ccnt,
                                                    int* __restrict__ coarse,
                                                    int* __restrict__ deg_src) {
    __shared__ int bc_cnt[128], bc_scan[128], bc_start[128], bc_cur[128], bc_gbase[128];
    __shared__ int stage[TILE];
    __shared__ unsigned char sbkt[TILE];
    int t = threadIdx.x;
    int g = blockIdx.x / TPG;
    int tile = blockIdx.x % TPG;
    int e0 = tile * TILE;
    int tile_n = min(TILE, EE - e0);
    const int* gs = a.src[g];
    const int* gd = a.dst[g];
    if (t < 128) bc_cnt[t] = 0;
    __syncthreads();
    int pw[16]; int pb[16];
#pragma unroll
    for (int i = 0; i < 16; i++) {
        int pos = i * 256 + t;
        pb[i] = -1;
        if (pos < tile_n) {
            int e = e0 + pos;
            int s = gs[e], d = gd[e];
            pw[i] = s | ((d & 511) << 16);
            pb[i] = d >> 9;
            atomicAdd(&bc_cnt[pb[i]], 1);
            if (g >= 4) atomicAdd(&deg_src[(g - 4) * NN + s], 1);
        }
    }
    __syncthreads();
    if (t < 128) bc_scan[t] = bc_cnt[t];
    __syncthreads();
    for (int off = 1; off < 128; off <<= 1) {
        int v = 0;
        if (t < 128 && t >= off) v = bc_scan[t - off];
        __syncthreads();
        if (t < 128) bc_scan[t] += v;
        __syncthreads();
    }
    if (t < 128) {
        int st = bc_scan[t] - bc_cnt[t];
        bc_start[t] = st;
        bc_cur[t] = st;
        bc_gbase[t] = (t < NBKT && bc_cnt[t] > 0) ? atomicAdd(&ccnt[g * NBKT + t], bc_cnt[t]) : 0;
    }
    __syncthreads();
#pragma unroll
    for (int i = 0; i < 16; i++) {
        if (pb[i] >= 0) {
            int slot = atomicAdd(&bc_cur[pb[i]], 1);
            stage[slot] = pw[i];
            sbkt[slot] = (unsigned char)pb[i];
        }
    }
    __syncthreads();
    for (int j = t; j < tile_n; j += 256) {
        int b = sbkt[j];
        int p = stage[j];
        int pos = bc_gbase[b] + (j - bc_start[b]);
        if (pos < CAP) coarse[(size_t)(g * NBKT + b) * CAP + pos] = p;
    }
}

// ---------------- per-graph exclusive scan of coarse bucket counts
__global__ void scanb_kernel(const int* __restrict__ ccnt, int* __restrict__ bktbase) {
    __shared__ int s[128];
    int g = blockIdx.x, t = threadIdx.x;
    int orig = (t < NBKT) ? min(ccnt[g * NBKT + t], CAP) : 0;
    s[t] = orig;
    __syncthreads();
    for (int off = 1; off < 128; off <<= 1) {
        int v = (t >= off) ? s[t - off] : 0;
        __syncthreads();
        s[t] += v;
        __syncthreads();
    }
    if (t < NBKT) bktbase[g * NBKT + t] = s[t] - orig;
}

// ---------------- pass 2: per (graph,bucket) counting sort -> final CSR + row_start + deg + ni
__global__ __launch_bounds__(256) void part2_kernel(const int* __restrict__ ccnt,
                                                    const int* __restrict__ bktbase,
                                                    const int* __restrict__ coarse,
                                                    int* __restrict__ bucket,
                                                    int* __restrict__ row_start,
                                                    int* __restrict__ dega,
                                                    float* __restrict__ nirm) {
    __shared__ int cnt5[512], off5[512], s2[256];
    __shared__ int spairs[CAP];
    __shared__ int ordered[CAP];
    int t = threadIdx.x;
    int g = blockIdx.x / NBKT;
    int b = blockIdx.x % NBKT;
    int n = min(ccnt[g * NBKT + b], CAP);
    int base = bktbase[g * NBKT + b];
    int node0 = b << 9;
    cnt5[t] = 0; cnt5[t + 256] = 0;
    __syncthreads();
    const int* pairs = coarse + (size_t)(g * NBKT + b) * CAP;
    for (int i = t; i < n; i += 256) {
        int p = pairs[i];
        spairs[i] = p;
        atomicAdd(&cnt5[p >> 16], 1);
    }
    __syncthreads();
    int pairsum = cnt5[2 * t] + cnt5[2 * t + 1];
    s2[t] = pairsum;
    __syncthreads();
    for (int off = 1; off < 256; off <<= 1) {
        int v = (t >= off) ? s2[t - off] : 0;
        __syncthreads();
        s2[t] += v;
        __syncthreads();
    }
    int ex = s2[t] - pairsum;
    off5[2 * t] = ex;
    off5[2 * t + 1] = ex + cnt5[2 * t];
    __syncthreads();
#pragma unroll
    for (int k = 0; k < 2; k++) {
        int j = 2 * t + k;
        int v = node0 + j;
        if (v < NN) {
            row_start[g * NN + v] = base + off5[j];
            int d = cnt5[j];
            dega[g * NN + v] = d;
            if (g >= 4) nirm[(g - 4) * NN + v] = (d > 0) ? rsqrtf((float)d) : 1.0f;
        }
    }
    __syncthreads();
    for (int i = t; i < n; i += 256) {
        int p = spairs[i];
        int slot = atomicAdd(&off5[p >> 16], 1);
        ordered[slot] = p & 0xFFFF;
    }
    __syncthreads();
    for (int i = t; i < n; i += 256) bucket[(size_t)g * EE + base + i] = ordered[i];
}

__global__ void normno_kernel(const int* __restrict__ deg_src, float* __restrict__ no) {
    int i = blockIdx.x * blockDim.x + threadIdx.x;
    if (i >= 4 * NN) return;
    int d = deg_src[i];
    no[i] = (d > 0) ? rsqrtf((float)d) : 1.0f;
}

// ---------------- fused aggregation: wave = 1 (graph,node), graph-pure 256-thread blocks,
// 8 graphs: g<4 = GAT (softmax+elu -> zout), g>=4 = GC agg (no/ni weights -> AGG fp16)
// packed-fp16 accumulation (v_pk_fma_f16)
__global__ __launch_bounds__(256) void agg_kernel(GatArgs ga, GcArgs gc, half_t* __restrict__ AGG,
                                                  const float* __restrict__ NO,
                                                  const float* __restrict__ NIrm,
                                                  const int* __restrict__ dega,
                                                  const int* __restrict__ row_start,
                                                  const int* __restrict__ bucket) {
    int g = blockIdx.x / 12500;
    int nb = blockIdx.x % 12500;
    int t = threadIdx.x;
    int wv = t >> 6, lane = t & 63;
    int q = lane >> 3, r = lane & 7;
    int v = nb * 4 + wv;
    int dg = dega[g * NN + v];
    int start = row_start[g * NN + v];
    const int* bk = bucket + (size_t)g * EE;
    HS acc;
#pragma unroll
    for (int j = 0; j < 4; j++) acc.i[j] = 0;

    if (g < 4) {
        // ---- GAT ----
        const float* el = ga.el[g];
        const half_t* fs = ga.fsrc[g];
        float er_v = ga.er[g][v];
        float s_l = 0.f;
        for (int base = 0; base < dg; base += 16) {
            int e0 = base + q, e1 = base + 8 + q;
            bool b0 = e0 < dg, b1 = e1 < dg;
            int s0 = b0 ? bk[start + e0] : 0;
            int s1 = b1 ? bk[start + e1] : 0;
            float w0 = 0.f, w1 = 0.f;
            if (b0) { float e = el[s0] + er_v; e = (e >= 0.f) ? e : NEG_SLOPE * e; w0 = expf(e); }
            if (b1) { float e = el[s1] + er_v; e = (e >= 0.f) ? e : NEG_SLOPE * e; w1 = expf(e); }
            s_l += w0 + w1;
            if (b0) {
                HS row; row.u = *(const uint4*)(fs + (size_t)s0 * DD + r * 8);
                half_t wh = (half_t)w0;
                half8 ws = {wh, wh, wh, wh, wh, wh, wh, wh};
                acc.h += row.h * ws;
            }
            if (b1) {
                HS row; row.u = *(const uint4*)(fs + (size_t)s1 * DD + r * 8);
                half_t wh = (half_t)w1;
                half8 ws = {wh, wh, wh, wh, wh, wh, wh, wh};
                acc.h += row.h * ws;
            }
        }
#pragma unroll
        for (int off = 8; off < 64; off <<= 1) {
            HS o;
#pragma unroll
            for (int j = 0; j < 4; j++) o.i[j] = __shfl_down(acc.i[j], off);
            acc.h += o.h;
            s_l += __shfl_down(s_l, off);
        }
        if (lane < 8) {
            float inv = (dg > 0) ? (1.0f / s_l) : 0.f;
            H8 o;
#pragma unroll
            for (int i = 0; i < 8; i++) {
                float x = (float)acc.h[i] * inv;
                x = (x > 0.f) ? x : expm1f(x);
                o.h[i] = (half_t)x;
            }
            *(uint4*)(ga.zout[g] + (size_t)v * 128 + r * 8) = o.u;
        }
    } else {
        // ---- GC aggregation ----
        int g4 = g - 4;
        const float* no = NO + g4 * NN;
        const half_t* feat = gc.feat[g4];
        for (int base = 0; base < dg; base += 16) {
            int e0 = base + q, e1 = base + 8 + q;
            bool b0 = e0 < dg, b1 = e1 < dg;
            int s0 = b0 ? bk[start + e0] : 0;
            int s1 = b1 ? bk[start + e1] : 0;
            float n0 = b0 ? no[s0] : 0.f;
            float n1 = b1 ? no[s1] : 0.f;
            if (b0) {
                HS row; row.u = *(const uint4*)(feat + (size_t)s0 * DD + r * 8);
                half_t nh = (half_t)n0;
                half8 ns = {nh, nh, nh, nh, nh, nh, nh, nh};
                acc.h += row.h * ns;
            }
            if (b1) {
                HS row; row.u = *(const uint4*)(feat + (size_t)s1 * DD + r * 8);
                half_t nh = (half_t)n1;
                half8 ns = {nh, nh, nh, nh, nh, nh, nh, nh};
                acc.h += row.h * ns;
            }
        }
#pragma unroll
        for (int off = 8; off < 64; off <<= 1) {
            HS o;
#pragma unroll
            for (int j = 0; j < 4; j++) o.i[j] = __shfl_down(acc.i[j], off);
            acc.h += o.h;
        }
        if (lane < 8) {
            float niv = NIrm[g4 * NN + v];
            H8 o;
#pragma unroll
            for (int i = 0; i < 8; i++) o.h[i] = (half_t)((float)acc.h[i] * niv);
            *(uint4*)(AGG + ((size_t)g4 * NN + v) * 64 + r * 8) = o.u;
        }
    }
}

// ---------------- GC transform: wave = 16-node tile, A from AGG, B = W16 fragments, 8 MFMA
__global__ __launch_bounds__(256) void trans_kernel(GcArgs gc, const half_t* __restrict__ AGG,
                                                    const half_t* __restrict__ W16,
                                                    const float* __restrict__ b_gc) {
    int t = threadIdx.x;
    int wv = t >> 6, lane = t & 63;
    int g = blockIdx.x / 782;
    int tile = (blockIdx.x % 782) * 4 + wv;
    if (tile >= 3125) return;
    int cl = lane & 15, quad = lane >> 4;
    const half_t* ab = AGG + ((size_t)g * NN + tile * 16 + cl) * 64;
    half8 A0 = *(const half8*)(ab + quad * 8);
    half8 A1 = *(const half8*)(ab + 32 + quad * 8);
    const half_t* wbase = W16 + (size_t)g * 8 * 64 * 8;
    half_t* hout = gc.hout[g];
#pragma unroll
    for (int nt = 0; nt < 4; nt++) {
        float bb = b_gc[g * 64 + nt * 16 + cl];
        f32x4 c = {bb, bb, bb, bb};
        half8 B0 = *(const half8*)(wbase + ((size_t)(nt * 2 + 0) * 64 + lane) * 8);
        half8 B1 = *(const half8*)(wbase + ((size_t)(nt * 2 + 1) * 64 + lane) * 8);
        c = __builtin_amdgcn_mfma_f32_16x16x32_f16(A0, B0, c, 0, 0, 0);
        c = __builtin_amdgcn_mfma_f32_16x16x32_f16(A1, B1, c, 0, 0, 0);
#pragma unroll
        for (int r_ = 0; r_ < 4; r_++) {
            int node = tile * 16 + quad * 4 + r_;
            float x = c[r_];
            x = (x > 0.f) ? x : expm1f(x);
            hout[(size_t)node * 128 + nt * 16 + cl] = (half_t)x;
        }
    }
}

// ---------------- semantic attention via MFMA (validated layout)
__global__ __launch_bounds__(256) void sem_att_kernel(SemArgs sa, float* __restrict__ wsum) {
    int inst = blockIdx.x >> 8;
    int blk  = blockIdx.x & 255;
    int t = threadIdx.x;
    int wv = t >> 6, lane = t & 63;
    int quad = lane >> 4, cl = lane & 15;
    const half_t* z = sa.z[inst];
    const float* W1 = sa.W1[inst];
    half8 Bf[8][2];
    float b1v[8], w2v[8];
#pragma unroll
    for (int nt = 0; nt < 8; nt++) {
        int n = nt * 16 + cl;
#pragma unroll
        for (int kh = 0; kh < 2; kh++) {
#pragma unroll
            for (int j = 0; j < 8; j++) {
                int k = kh * 32 + quad * 8 + j;
                Bf[nt][kh][j] = (half_t)W1[k * HHID + n];
            }
        }
        b1v[nt] = sa.b1[inst][n];
        w2v[nt] = sa.w2[inst][n];
    }
    float local0 = 0.f, local1 = 0.f;
    int wave_id = blk * 4 + wv;
    for (int tile = wave_id; tile < 6250; tile += 1024) {
        int m = (tile >= 3125) ? 1 : 0;
        int node = (tile - m * 3125) * 16 + cl;
        const half_t* zr = z + (size_t)node * 128 + m * 64 + quad * 8;
        half8 A0 = *(const half8*)(zr);
        half8 A1 = *(const half8*)(zr + 32);
        float sumv = 0.f;
#pragma unroll
        for (int nt = 0; nt < 8; nt++) {
            f32x4 c = {0.f, 0.f, 0.f, 0.f};
            c = __builtin_amdgcn_mfma_f32_16x16x32_f16(A0, Bf[nt][0], c, 0, 0, 0);
            c = __builtin_amdgcn_mfma_f32_16x16x32_f16(A1, Bf[nt][1], c, 0, 0, 0);
#pragma unroll
            for (int r = 0; r < 4; r++) sumv += tanhf(c[r] + b1v[nt]) * w2v[nt];
        }
#pragma unroll
        for (int off = 32; off > 0; off >>= 1) sumv += __shfl_down(sumv, off);
        if (lane == 0) { if (m == 0) local0 += sumv; else local1 += sumv; }
    }
    if (lane == 0) {
        if (local0 != 0.f) atomicAdd(&wsum[inst * 2 + 0], local0);
        if (local1 != 0.f) atomicAdd(&wsum[inst * 2 + 1], local1);
    }
}

// ---------------- final combine: thread = 4 consecutive output cols
__global__ void combine_kernel(const half_t* __restrict__ ZU, const half_t* __restrict__ ZI,
                               const half_t* __restrict__ HU, const half_t* __restrict__ HI,
                               const float* __restrict__ wsum, float* __restrict__ out) {
    int gid = blockIdx.x * blockDim.x + threadIdx.x;
    if (gid >= (NU + NI) * 16) return;
    int node = gid >> 4;
    int c4 = (gid & 15) * 4;
    const half_t* zb; const half_t* hb;
    float wr0, wr1, wh0, wh1;
    int idx;
    if (node < NU) {
        zb = ZU; hb = HU; idx = node;
        wr0 = wsum[0]; wr1 = wsum[1]; wh0 = wsum[4]; wh1 = wsum[5];
    } else {
        zb = ZI; hb = HI; idx = node - NU;
        wr0 = wsum[2]; wr1 = wsum[3]; wh0 = wsum[6]; wh1 = wsum[7];
    }
    const float inv_n = 1.0f / 50000.0f;
    wr0 *= inv_n; wr1 *= inv_n; wh0 *= inv_n; wh1 *= inv_n;
    float m = fmaxf(wr0, wr1);
    float e0 = expf(wr0 - m), e1 = expf(wr1 - m);
    float br0 = e0 / (e0 + e1), br1 = e1 / (e0 + e1);
    m = fmaxf(wh0, wh1);
    e0 = expf(wh0 - m); e1 = expf(wh1 - m);
    float bh0 = e0 / (e0 + e1), bh1 = e1 / (e0 + e1);
    H4 z0, z1, h0, h1;
    z0.u = *(const uint2*)(zb + (size_t)idx * 128 + c4);
    z1.u = *(const uint2*)(zb + (size_t)idx * 128 + 64 + c4);
    h0.u = *(const uint2*)(hb + (size_t)idx * 128 + c4);
    h1.u = *(const uint2*)(hb + (size_t)idx * 128 + 64 + c4);
    float4 o;
    o.x = (float)z0.h[0] * br0 + (float)z1.h[0] * br1 + (float)h0.h[0] * bh0 + (float)h1.h[0] * bh1;
    o.y = (float)z0.h[1] * br0 + (float)z1.h[1] * br1 + (float)h0.h[1] * bh0 + (float)h1.h[1] * bh1;
    o.z = (float)z0.h[2] * br0 + (float)z1.h[2] * br1 + (float)h0.h[2] * bh0 + (float)h1.h[2] * bh1;
    o.w = (float)z0.h[3] * br0 + (float)z1.h[3] * br1 + (float)h0.h[3] * bh0 + (float)h1.h[3] * bh1;
    *(float4*)(out + (size_t)node * 64 + c4) = o;
}

extern "C" void kernel_launch(void* const* d_in, const int* in_sizes, int n_in,
                              void* d_out, int out_size, void* d_ws, size_t ws_size,
                              hipStream_t stream) {
    const float* feat_user = (const float*)d_in[0];
    const float* feat_item = (const float*)d_in[1];
    const float* attn_l    = (const float*)d_in[2];
    const float* attn_r    = (const float*)d_in[3];
    const float* W_gc      = (const float*)d_in[4];
    const float* b_gc      = (const float*)d_in[5];
    const float* sa_rel_W1 = (const float*)d_in[6];
    const float* sa_rel_b1 = (const float*)d_in[7];
    const float* sa_rel_w2 = (const float*)d_in[8];
    const float* sa_u_W1   = (const float*)d_in[9];
    const float* sa_u_b1   = (const float*)d_in[10];
    const float* sa_u_w2   = (const float*)d_in[11];
    const float* sa_i_W1   = (const float*)d_in[12];
    const float* sa_i_b1   = (const float*)d_in[13];
    const float* sa_i_w2   = (const float*)d_in[14];
    const int* rel_u_src = (const int*)d_in[15];
    const int* rel_u_dst = (const int*)d_in[16];
    const int* rel_i_src = (const int*)d_in[17];
    const int* rel_i_dst = (const int*)d_in[18];
    const int* mp_u_src  = (const int*)d_in[19];
    const int* mp_u_dst  = (const int*)d_in[20];
    const int* mp_i_src  = (const int*)d_in[21];
    const int* mp_i_dst  = (const int*)d_in[22];

    // ---- workspace layout ----
    half_t* ZU   = (half_t*)d_ws;             // NN*128 fp16
    half_t* ZI   = ZU + NN * 128;
    half_t* HU   = ZI + NN * 128;
    half_t* HI   = HU + NN * 128;
    half_t* FBU  = HI + NN * 128;             // fp16 feat_user, NN*64
    half_t* FBI  = FBU + NN * 64;             // fp16 feat_item, NN*64
    float*  DI   = (float*)(FBI + NN * 64);   // 4*NN
    float*  DU   = DI + 4 * NN;               // 4*NN
    float*  NO   = DU + 4 * NN;               // 4*NN
    float*  NIrm = NO + 4 * NN;               // 4*NN
    int*    ROW  = (int*)(NIrm + 4 * NN);     // 8*NN
    int*    DEGA = ROW + 8 * NN;              // 8*NN
    int*    BUCKET = DEGA + 8 * NN;           // 8*EE
    int*    BKTBASE = BUCKET + 8 * EE;        // 8*128
    int*    CCNT = BKTBASE + 8 * 128;         // 8*128  -- zeroed
    int*    DEG_SRC = CCNT + 8 * 128;         // 4*NN   -- zeroed
    float*  WSUM = (float*)(DEG_SRC + 4 * NN);// 8      -- zeroed
    half_t* W16  = (half_t*)(WSUM + 8);       // 4*4096 fp16 fragment-ordered W
    half_t* AGG  = W16 + 4 * 4096;            // 4*NN*64 fp16 GC aggregation buffer
    int*    COARSE = (int*)d_ws;              // 8*98*CAP ints, aliases ZU..; dead before agg

    hipMemsetAsync(CCNT, 0, (size_t)(8 * 128 + 4 * NN) * sizeof(int) + 8 * sizeof(float), stream);

    // ---- W fragment prep + fused fp16-cvt + dots ----
    prepw_kernel<<<4, 64, 0, stream>>>(W_gc, W16);
    Ptr4c vi = {{ attn_l + 0 * DD, attn_l + 1 * DD, attn_r + 2 * DD, attn_r + 3 * DD }};
    Ptr4m oi = {{ DI, DI + NI, DI + 2 * NI, DI + 3 * NI }};
    Ptr4c vu = {{ attn_l + 2 * DD, attn_l + 3 * DD, attn_r + 0 * DD, attn_r + 1 * DD }};
    Ptr4m ou = {{ DU, DU + NU, DU + 2 * NU, DU + 3 * NU }};
    dot4_kernel<<<(NN / 4 * 64) / 256, 256, 0, stream>>>(feat_item, vi, oi, FBI, NI);
    dot4_kernel<<<(NN / 4 * 64) / 256, 256, 0, stream>>>(feat_user, vu, ou, FBU, NU);

    // ---- CSR build ----
    EdgeArgs ea;
    ea.src[0] = rel_u_src;      ea.dst[0] = rel_u_dst;
    ea.src[1] = rel_u_src + EE; ea.dst[1] = rel_u_dst + EE;
    ea.src[2] = rel_i_src;      ea.dst[2] = rel_i_dst;
    ea.src[3] = rel_i_src + EE; ea.dst[3] = rel_i_dst + EE;
    ea.src[4] = mp_u_src;       ea.dst[4] = mp_u_dst;
    ea.src[5] = mp_u_src + EE;  ea.dst[5] = mp_u_dst + EE;
    ea.src[6] = mp_i_src;       ea.dst[6] = mp_i_dst;
    ea.src[7] = mp_i_src + EE;  ea.dst[7] = mp_i_dst + EE;

    part1_kernel<<<8 * TPG, 256, 0, stream>>>(ea, CCNT, COARSE, DEG_SRC);
    scanb_kernel<<<8, 128, 0, stream>>>(CCNT, BKTBASE);
    part2_kernel<<<8 * NBKT, 256, 0, stream>>>(CCNT, BKTBASE, COARSE, BUCKET, ROW, DEGA, NIrm);
    normno_kernel<<<(4 * NN + 255) / 256, 256, 0, stream>>>(DEG_SRC, NO);

    // ---- fused aggregation (8 graphs, wave = node) ----
    GatArgs ga;
    ga.el[0] = DI;          ga.er[0] = DU + 2 * NU; ga.fsrc[0] = FBI; ga.zout[0] = ZU;
    ga.el[1] = DI + NI;     ga.er[1] = DU + 3 * NU; ga.fsrc[1] = FBI; ga.zout[1] = ZU + 64;
    ga.el[2] = DU;          ga.er[2] = DI + 2 * NI; ga.fsrc[2] = FBU; ga.zout[2] = ZI;
    ga.el[3] = DU + NU;     ga.er[3] = DI + 3 * NI; ga.fsrc[3] = FBU; ga.zout[3] = ZI + 64;
    GcArgs gc;
    gc.feat[0] = FBU; gc.hout[0] = HU;
    gc.feat[1] = FBU; gc.hout[1] = HU + 64;
    gc.feat[2] = FBI; gc.hout[2] = HI;
    gc.feat[3] = FBI; gc.hout[3] = HI + 64;
    agg_kernel<<<8 * 12500, 256, 0, stream>>>(ga, gc, AGG, NO, NIrm, DEGA, ROW, BUCKET);

    // ---- GC MFMA transform ----
    trans_kernel<<<4 * 782, 256, 0, stream>>>(gc, AGG, W16, b_gc);

    // ---- semantic attention (single launch, 4 instances, MFMA) ----
    SemArgs sa;
    sa.z[0] = ZU; sa.W1[0] = sa_rel_W1; sa.b1[0] = sa_rel_b1; sa.w2[0] = sa_rel_w2;
    sa.z[1] = ZI; sa.W1[1] = sa_rel_W1; sa.b1[1] = sa_rel_b1; sa.w2[1] = sa_rel_w2;
    sa.z[2] = HU; sa.W1[2] = sa_u_W1;   sa.b1[2] = sa_u_b1;   sa.w2[2] = sa_u_w2;
    sa.z[3] = HI; sa.W1[3] = sa_i_W1;   sa.b1[3] = sa_i_b1;   sa.w2[3] = sa_i_w2;
    sem_att_kernel<<<4 * 256, 256, 0, stream>>>(sa, WSUM);

    // ---- combine ----
    combine_kernel<<<((NU + NI) * 16 + 255) / 256, 256, 0, stream>>>(ZU, ZI, HU, HI, WSUM, (float*)d_out);
}

// Round 11
// 567.263 us; speedup vs baseline: 1.2053x; 1.0238x over previous
//
#include <hip/hip_runtime.h>
#include <math.h>

#define NU 50000
#define NI 50000
#define NN 50000
#define DD 64
#define HHID 128
#define EE 500000
#define NEG_SLOPE 0.01f
#define NBKT 98            // coarse buckets of 512 nodes (dst>>9)
#define CAP 6144           // capacity per (graph,bucket) coarse region
#define TILE 4096
#define TPG 123            // tiles per graph = ceil(500000/4096)

typedef _Float16 half_t;
typedef _Float16 half8 __attribute__((ext_vector_type(8)));
typedef float f32x4 __attribute__((ext_vector_type(4)));
union H4 { uint2 u; half_t h[4]; };
union H8 { uint4 u; half_t h[8]; };
union HS { half8 h; int i[4]; uint4 u; };
union HC { unsigned short us; half_t h; };

struct Ptr4c { const float* p[4]; };
struct Ptr4m { float*       p[4]; };
struct EdgeArgs { const int* src[8]; const int* dst[8]; };
struct GatArgs { const half_t* fsrc[4]; half_t* zout[4]; };
struct GcArgs  { const half_t* feat[4]; half_t* hout[4]; };
struct WArgs   { const float* el[4]; const float* er[4]; const int* deg_src; };
struct SemArgs { const half_t* z[4]; const float* W1[4]; const float* b1[4]; const float* w2[4]; };

// ---------------- fused: fp32 feat -> fp16 table + 4 per-node dots; wave = 4 nodes x 16 lanes
__global__ void dot4_kernel(const float* __restrict__ feat, Ptr4c vecs, Ptr4m outs,
                            half_t* __restrict__ fb16, int n) {
    int gid = blockIdx.x * blockDim.x + threadIdx.x;
    int w = gid >> 6;
    int lane = threadIdx.x & 63;
    int sub = lane >> 4, r = lane & 15;
    int node = w * 4 + sub;
    if (node >= n) return;
    float4 f = *(const float4*)(feat + (size_t)node * DD + r * 4);
    H4 o16;
    o16.h[0] = (half_t)f.x; o16.h[1] = (half_t)f.y; o16.h[2] = (half_t)f.z; o16.h[3] = (half_t)f.w;
    *(uint2*)(fb16 + (size_t)node * DD + r * 4) = o16.u;
#pragma unroll
    for (int j = 0; j < 4; j++) {
        float4 vv = *(const float4*)(vecs.p[j] + r * 4);
        float val = f.x * vv.x + f.y * vv.y + f.z * vv.z + f.w * vv.w;
        val += __shfl_down(val, 8);
        val += __shfl_down(val, 4);
        val += __shfl_down(val, 2);
        val += __shfl_down(val, 1);
        if (r == 0) outs.p[j][node] = val;
    }
}

// ---------------- W_gc -> fragment-ordered fp16: W16[((g*8 + nt*2+kh)*64 + lane)*8 + j]
__global__ void prepw_kernel(const float* __restrict__ W_gc, half_t* __restrict__ W16) {
    int g = blockIdx.x;
    int lane = threadIdx.x;
    int cl = lane & 15, quad = lane >> 4;
#pragma unroll
    for (int nt = 0; nt < 4; nt++) {
#pragma unroll
        for (int kh = 0; kh < 2; kh++) {
            H8 o;
#pragma unroll
            for (int j = 0; j < 8; j++) {
                int k = kh * 32 + quad * 8 + j;
                int n = nt * 16 + cl;
                o.h[j] = (half_t)W_gc[g * 4096 + k * 64 + n];
            }
            *(uint4*)(W16 + ((size_t)(g * 8 + nt * 2 + kh) * 64 + lane) * 8) = o.u;
        }
    }
}

// ---------------- pass 1: LDS counting-sort partition by dst>>9; packed record src|(dst&511)<<16
__global__ __launch_bounds__(256) void part1_kernel(EdgeArgs a, int* __restrict__ ccnt,
                                                    int* __restrict__ coarse,
                                                    int* __restrict__ deg_src) {
    __shared__ int bc_cnt[128], bc_scan[128], bc_start[128], bc_cur[128], bc_gbase[128];
    __shared__ int stage[TILE];
    __shared__ unsigned char sbkt[TILE];
    int t = threadIdx.x;
    int g = blockIdx.x / TPG;
    int tile = blockIdx.x % TPG;
    int e0 = tile * TILE;
    int tile_n = min(TILE, EE - e0);
    const int* gs = a.src[g];
    const int* gd = a.dst[g];
    if (t < 128) bc_cnt[t] = 0;
    __syncthreads();
    int pw[16]; int pb[16];
#pragma unroll
    for (int i = 0; i < 16; i++) {
        int pos = i * 256 + t;
        pb[i] = -1;
        if (pos < tile_n) {
            int e = e0 + pos;
            int s = gs[e], d = gd[e];
            pw[i] = s | ((d & 511) << 16);
            pb[i] = d >> 9;
            atomicAdd(&bc_cnt[pb[i]], 1);
            if (g >= 4) atomicAdd(&deg_src[(g - 4) * NN + s], 1);
        }
    }
    __syncthreads();
    if (t < 128) bc_scan[t] = bc_cnt[t];
    __syncthreads();
    for (int off = 1; off < 128; off <<= 1) {
        int v = 0;
        if (t < 128 && t >= off) v = bc_scan[t - off];
        __syncthreads();
        if (t < 128) bc_scan[t] += v;
        __syncthreads();
    }
    if (t < 128) {
        int st = bc_scan[t] - bc_cnt[t];
        bc_start[t] = st;
        bc_cur[t] = st;
        bc_gbase[t] = (t < NBKT && bc_cnt[t] > 0) ? atomicAdd(&ccnt[g * NBKT + t], bc_cnt[t]) : 0;
    }
    __syncthreads();
#pragma unroll
    for (int i = 0; i < 16; i++) {
        if (pb[i] >= 0) {
            int slot = atomicAdd(&bc_cur[pb[i]], 1);
            stage[slot] = pw[i];
            sbkt[slot] = (unsigned char)pb[i];
        }
    }
    __syncthreads();
    for (int j = t; j < tile_n; j += 256) {
        int b = sbkt[j];
        int p = stage[j];
        int pos = bc_gbase[b] + (j - bc_start[b]);
        if (pos < CAP) coarse[(size_t)(g * NBKT + b) * CAP + pos] = p;
    }
}

// ---------------- per-graph exclusive scan of coarse bucket counts
__global__ void scanb_kernel(const int* __restrict__ ccnt, int* __restrict__ bktbase) {
    __shared__ int s[128];
    int g = blockIdx.x, t = threadIdx.x;
    int orig = (t < NBKT) ? min(ccnt[g * NBKT + t], CAP) : 0;
    s[t] = orig;
    __syncthreads();
    for (int off = 1; off < 128; off <<= 1) {
        int v = (t >= off) ? s[t - off] : 0;
        __syncthreads();
        s[t] += v;
        __syncthreads();
    }
    if (t < NBKT) bktbase[g * NBKT + t] = s[t] - orig;
}

// ---------------- pass 2: per (graph,bucket) counting sort -> CSR with packed (w16<<16 | src),
// row_start, deg, ni; edge weights computed HERE (once per edge)
__global__ __launch_bounds__(256) void part2_kernel(const int* __restrict__ ccnt,
                                                    const int* __restrict__ bktbase,
                                                    const int* __restrict__ coarse,
                                                    WArgs wa,
                                                    int* __restrict__ bucket,
                                                    int* __restrict__ row_start,
                                                    int* __restrict__ dega,
                                                    float* __restrict__ nirm) {
    __shared__ int cnt5[512], off5[512], s2[256];
    __shared__ int spairs[CAP];
    __shared__ int ordered[CAP];
    int t = threadIdx.x;
    int g = blockIdx.x / NBKT;
    int b = blockIdx.x % NBKT;
    int n = min(ccnt[g * NBKT + b], CAP);
    int base = bktbase[g * NBKT + b];
    int node0 = b << 9;
    cnt5[t] = 0; cnt5[t + 256] = 0;
    __syncthreads();
    const int* pairs = coarse + (size_t)(g * NBKT + b) * CAP;
    for (int i = t; i < n; i += 256) {
        int p = pairs[i];
        spairs[i] = p;
        atomicAdd(&cnt5[p >> 16], 1);
    }
    __syncthreads();
    int pairsum = cnt5[2 * t] + cnt5[2 * t + 1];
    s2[t] = pairsum;
    __syncthreads();
    for (int off = 1; off < 256; off <<= 1) {
        int v = (t >= off) ? s2[t - off] : 0;
        __syncthreads();
        s2[t] += v;
        __syncthreads();
    }
    int ex = s2[t] - pairsum;
    off5[2 * t] = ex;
    off5[2 * t + 1] = ex + cnt5[2 * t];
    __syncthreads();
#pragma unroll
    for (int k = 0; k < 2; k++) {
        int j = 2 * t + k;
        int v = node0 + j;
        if (v < NN) {
            row_start[g * NN + v] = base + off5[j];
            int d = cnt5[j];
            dega[g * NN + v] = d;
            if (g >= 4) nirm[(g - 4) * NN + v] = (d > 0) ? rsqrtf((float)d) : 1.0f;
        }
    }
    __syncthreads();
    for (int i = t; i < n; i += 256) {
        int p = spairs[i];
        int src = p & 0xFFFF;
        int ldst = p >> 16;
        float wf;
        if (g < 4) {
            float e = wa.el[g][src] + wa.er[g][node0 + ldst];
            e = (e >= 0.f) ? e : NEG_SLOPE * e;
            wf = expf(e);
        } else {
            wf = rsqrtf((float)wa.deg_src[(g - 4) * NN + src]);
        }
        HC cv; cv.h = (half_t)wf;
        int slot = atomicAdd(&off5[ldst], 1);
        ordered[slot] = src | ((int)cv.us << 16);
    }
    __syncthreads();
    for (int i = t; i < n; i += 256) bucket[(size_t)g * EE + base + i] = ordered[i];
}

// ---------------- fused aggregation: wave = 1 (graph,node), packed (w|src) CSR entries,
// g<4 = GAT (softmax+elu -> zout), g>=4 = GC agg (-> AGG fp16); packed-fp16 accumulation
__global__ __launch_bounds__(256) void agg_kernel(GatArgs ga, GcArgs gc, half_t* __restrict__ AGG,
                                                  const float* __restrict__ NIrm,
                                                  const int* __restrict__ dega,
                                                  const int* __restrict__ row_start,
                                                  const int* __restrict__ bucket) {
    int g = blockIdx.x / 12500;
    int nb = blockIdx.x % 12500;
    int t = threadIdx.x;
    int wv = t >> 6, lane = t & 63;
    int q = lane >> 3, r = lane & 7;
    int v = nb * 4 + wv;
    int dg = dega[g * NN + v];
    int start = row_start[g * NN + v];
    const int* bk = bucket + (size_t)g * EE;
    const half_t* feat = (g < 4) ? ga.fsrc[g] : gc.feat[g - 4];
    HS acc;
#pragma unroll
    for (int j = 0; j < 4; j++) acc.i[j] = 0;
    float s_l = 0.f;
    for (int base = 0; base < dg; base += 16) {
        int e0 = base + q, e1 = base + 8 + q;
        bool b0 = e0 < dg, b1 = e1 < dg;
        int p0 = b0 ? bk[start + e0] : 0;
        int p1 = b1 ? bk[start + e1] : 0;
        HC c0, c1;
        c0.us = (unsigned short)((unsigned)p0 >> 16);
        c1.us = (unsigned short)((unsigned)p1 >> 16);
        s_l += (float)c0.h + (float)c1.h;          // masked entries have w bits = 0
        if (b0) {
            int s0 = p0 & 0xFFFF;
            HS row; row.u = *(const uint4*)(feat + (size_t)s0 * DD + r * 8);
            half_t wh = c0.h;
            half8 ws = {wh, wh, wh, wh, wh, wh, wh, wh};
            acc.h += row.h * ws;
        }
        if (b1) {
            int s1 = p1 & 0xFFFF;
            HS row; row.u = *(const uint4*)(feat + (size_t)s1 * DD + r * 8);
            half_t wh = c1.h;
            half8 ws = {wh, wh, wh, wh, wh, wh, wh, wh};
            acc.h += row.h * ws;
        }
    }
#pragma unroll
    for (int off = 8; off < 64; off <<= 1) {
        HS o;
#pragma unroll
        for (int j = 0; j < 4; j++) o.i[j] = __shfl_down(acc.i[j], off);
        acc.h += o.h;
        s_l += __shfl_down(s_l, off);
    }
    if (lane < 8) {
        if (g < 4) {
            float inv = (dg > 0) ? (1.0f / s_l) : 0.f;
            H8 o;
#pragma unroll
            for (int i = 0; i < 8; i++) {
                float x = (float)acc.h[i] * inv;
                x = (x > 0.f) ? x : expm1f(x);
                o.h[i] = (half_t)x;
            }
            *(uint4*)(ga.zout[g] + (size_t)v * 128 + r * 8) = o.u;
        } else {
            float niv = NIrm[(g - 4) * NN + v];
            H8 o;
#pragma unroll
            for (int i = 0; i < 8; i++) o.h[i] = (half_t)((float)acc.h[i] * niv);
            *(uint4*)(AGG + ((size_t)(g - 4) * NN + v) * 64 + r * 8) = o.u;
        }
    }
}

// ---------------- GC transform: wave = 16-node tile, A from AGG, B = W16 fragments, 8 MFMA
__global__ __launch_bounds__(256) void trans_kernel(GcArgs gc, const half_t* __restrict__ AGG,
                                                    const half_t* __restrict__ W16,
                                                    const float* __restrict__ b_gc) {
    int t = threadIdx.x;
    int wv = t >> 6, lane = t & 63;
    int g = blockIdx.x / 782;
    int tile = (blockIdx.x % 782) * 4 + wv;
    if (tile >= 3125) return;
    int cl = lane & 15, quad = lane >> 4;
    const half_t* ab = AGG + ((size_t)g * NN + tile * 16 + cl) * 64;
    half8 A0 = *(const half8*)(ab + quad * 8);
    half8 A1 = *(const half8*)(ab + 32 + quad * 8);
    const half_t* wbase = W16 + (size_t)g * 8 * 64 * 8;
    half_t* hout = gc.hout[g];
#pragma unroll
    for (int nt = 0; nt < 4; nt++) {
        float bb = b_gc[g * 64 + nt * 16 + cl];
        f32x4 c = {bb, bb, bb, bb};
        half8 B0 = *(const half8*)(wbase + ((size_t)(nt * 2 + 0) * 64 + lane) * 8);
        half8 B1 = *(const half8*)(wbase + ((size_t)(nt * 2 + 1) * 64 + lane) * 8);
        c = __builtin_amdgcn_mfma_f32_16x16x32_f16(A0, B0, c, 0, 0, 0);
        c = __builtin_amdgcn_mfma_f32_16x16x32_f16(A1, B1, c, 0, 0, 0);
#pragma unroll
        for (int r_ = 0; r_ < 4; r_++) {
            int node = tile * 16 + quad * 4 + r_;
            float x = c[r_];
            x = (x > 0.f) ? x : expm1f(x);
            hout[(size_t)node * 128 + nt * 16 + cl] = (half_t)x;
        }
    }
}

// ---------------- semantic attention via MFMA (validated layout)
__global__ __launch_bounds__(256) void sem_att_kernel(SemArgs sa, float* __restrict__ wsum) {
    int inst = blockIdx.x >> 8;
    int blk  = blockIdx.x & 255;
    int t = threadIdx.x;
    int wv = t >> 6, lane = t & 63;
    int quad = lane >> 4, cl = lane & 15;
    const half_t* z = sa.z[inst];
    const float* W1 = sa.W1[inst];
    half8 Bf[8][2];
    float b1v[8], w2v[8];
#pragma unroll
    for (int nt = 0; nt < 8; nt++) {
        int n = nt * 16 + cl;
#pragma unroll
        for (int kh = 0; kh < 2; kh++) {
#pragma unroll
            for (int j = 0; j < 8; j++) {
                int k = kh * 32 + quad * 8 + j;
                Bf[nt][kh][j] = (half_t)W1[k * HHID + n];
            }
        }
        b1v[nt] = sa.b1[inst][n];
        w2v[nt] = sa.w2[inst][n];
    }
    float local0 = 0.f, local1 = 0.f;
    int wave_id = blk * 4 + wv;
    for (int tile = wave_id; tile < 6250; tile += 1024) {
        int m = (tile >= 3125) ? 1 : 0;
        int node = (tile - m * 3125) * 16 + cl;
        const half_t* zr = z + (size_t)node * 128 + m * 64 + quad * 8;
        half8 A0 = *(const half8*)(zr);
        half8 A1 = *(const half8*)(zr + 32);
        float sumv = 0.f;
#pragma unroll
        for (int nt = 0; nt < 8; nt++) {
            f32x4 c = {0.f, 0.f, 0.f, 0.f};
            c = __builtin_amdgcn_mfma_f32_16x16x32_f16(A0, Bf[nt][0], c, 0, 0, 0);
            c = __builtin_amdgcn_mfma_f32_16x16x32_f16(A1, Bf[nt][1], c, 0, 0, 0);
#pragma unroll
            for (int r = 0; r < 4; r++) sumv += tanhf(c[r] + b1v[nt]) * w2v[nt];
        }
#pragma unroll
        for (int off = 32; off > 0; off >>= 1) sumv += __shfl_down(sumv, off);
        if (lane == 0) { if (m == 0) local0 += sumv; else local1 += sumv; }
    }
    if (lane == 0) {
        if (local0 != 0.f) atomicAdd(&wsum[inst * 2 + 0], local0);
        if (local1 != 0.f) atomicAdd(&wsum[inst * 2 + 1], local1);
    }
}

// ---------------- final combine: thread = 4 consecutive output cols
__global__ void combine_kernel(const half_t* __restrict__ ZU, const half_t* __restrict__ ZI,
                               const half_t* __restrict__ HU, const half_t* __restrict__ HI,
                               const float* __restrict__ wsum, float* __restrict__ out) {
    int gid = blockIdx.x * blockDim.x + threadIdx.x;
    if (gid >= (NU + NI) * 16) return;
    int node = gid >> 4;
    int c4 = (gid & 15) * 4;
    const half_t* zb; const half_t* hb;
    float wr0, wr1, wh0, wh1;
    int idx;
    if (node < NU) {
        zb = ZU; hb = HU; idx = node;
        wr0 = wsum[0]; wr1 = wsum[1]; wh0 = wsum[4]; wh1 = wsum[5];
    } else {
        zb = ZI; hb = HI; idx = node - NU;
        wr0 = wsum[2]; wr1 = wsum[3]; wh0 = wsum[6]; wh1 = wsum[7];
    }
    const float inv_n = 1.0f / 50000.0f;
    wr0 *= inv_n; wr1 *= inv_n; wh0 *= inv_n; wh1 *= inv_n;
    float m = fmaxf(wr0, wr1);
    float e0 = expf(wr0 - m), e1 = expf(wr1 - m);
    float br0 = e0 / (e0 + e1), br1 = e1 / (e0 + e1);
    m = fmaxf(wh0, wh1);
    e0 = expf(wh0 - m); e1 = expf(wh1 - m);
    float bh0 = e0 / (e0 + e1), bh1 = e1 / (e0 + e1);
    H4 z0, z1, h0, h1;
    z0.u = *(const uint2*)(zb + (size_t)idx * 128 + c4);
    z1.u = *(const uint2*)(zb + (size_t)idx * 128 + 64 + c4);
    h0.u = *(const uint2*)(hb + (size_t)idx * 128 + c4);
    h1.u = *(const uint2*)(hb + (size_t)idx * 128 + 64 + c4);
    float4 o;
    o.x = (float)z0.h[0] * br0 + (float)z1.h[0] * br1 + (float)h0.h[0] * bh0 + (float)h1.h[0] * bh1;
    o.y = (float)z0.h[1] * br0 + (float)z1.h[1] * br1 + (float)h0.h[1] * bh0 + (float)h1.h[1] * bh1;
    o.z = (float)z0.h[2] * br0 + (float)z1.h[2] * br1 + (float)h0.h[2] * bh0 + (float)h1.h[2] * bh1;
    o.w = (float)z0.h[3] * br0 + (float)z1.h[3] * br1 + (float)h0.h[3] * bh0 + (float)h1.h[3] * bh1;
    *(float4*)(out + (size_t)node * 64 + c4) = o;
}

extern "C" void kernel_launch(void* const* d_in, const int* in_sizes, int n_in,
                              void* d_out, int out_size, void* d_ws, size_t ws_size,
                              hipStream_t stream) {
    const float* feat_user = (const float*)d_in[0];
    const float* feat_item = (const float*)d_in[1];
    const float* attn_l    = (const float*)d_in[2];
    const float* attn_r    = (const float*)d_in[3];
    const float* W_gc      = (const float*)d_in[4];
    const float* b_gc      = (const float*)d_in[5];
    const float* sa_rel_W1 = (const float*)d_in[6];
    const float* sa_rel_b1 = (const float*)d_in[7];
    const float* sa_rel_w2 = (const float*)d_in[8];
    const float* sa_u_W1   = (const float*)d_in[9];
    const float* sa_u_b1   = (const float*)d_in[10];
    const float* sa_u_w2   = (const float*)d_in[11];
    const float* sa_i_W1   = (const float*)d_in[12];
    const float* sa_i_b1   = (const float*)d_in[13];
    const float* sa_i_w2   = (const float*)d_in[14];
    const int* rel_u_src = (const int*)d_in[15];
    const int* rel_u_dst = (const int*)d_in[16];
    const int* rel_i_src = (const int*)d_in[17];
    const int* rel_i_dst = (const int*)d_in[18];
    const int* mp_u_src  = (const int*)d_in[19];
    const int* mp_u_dst  = (const int*)d_in[20];
    const int* mp_i_src  = (const int*)d_in[21];
    const int* mp_i_dst  = (const int*)d_in[22];

    // ---- workspace layout ----
    half_t* ZU   = (half_t*)d_ws;             // NN*128 fp16
    half_t* ZI   = ZU + NN * 128;
    half_t* HU   = ZI + NN * 128;
    half_t* HI   = HU + NN * 128;
    half_t* FBU  = HI + NN * 128;             // fp16 feat_user, NN*64
    half_t* FBI  = FBU + NN * 64;             // fp16 feat_item, NN*64
    float*  DI   = (float*)(FBI + NN * 64);   // 4*NN
    float*  DU   = DI + 4 * NN;               // 4*NN
    float*  NIrm = DU + 4 * NN;               // 4*NN
    int*    ROW  = (int*)(NIrm + 4 * NN);     // 8*NN
    int*    DEGA = ROW + 8 * NN;              // 8*NN
    int*    BUCKET = DEGA + 8 * NN;           // 8*EE (packed w16|src)
    int*    BKTBASE = BUCKET + 8 * EE;        // 8*128
    int*    CCNT = BKTBASE + 8 * 128;         // 8*128  -- zeroed
    int*    DEG_SRC = CCNT + 8 * 128;         // 4*NN   -- zeroed
    float*  WSUM = (float*)(DEG_SRC + 4 * NN);// 8      -- zeroed
    half_t* W16  = (half_t*)(WSUM + 8);       // 4*4096 fp16 fragment-ordered W
    half_t* AGG  = W16 + 4 * 4096;            // 4*NN*64 fp16 GC aggregation buffer
    int*    COARSE = (int*)d_ws;              // 8*98*CAP ints, aliases ZU..; dead before agg

    hipMemsetAsync(CCNT, 0, (size_t)(8 * 128 + 4 * NN) * sizeof(int) + 8 * sizeof(float), stream);

    // ---- W fragment prep + fused fp16-cvt + dots ----
    prepw_kernel<<<4, 64, 0, stream>>>(W_gc, W16);
    Ptr4c vi = {{ attn_l + 0 * DD, attn_l + 1 * DD, attn_r + 2 * DD, attn_r + 3 * DD }};
    Ptr4m oi = {{ DI, DI + NI, DI + 2 * NI, DI + 3 * NI }};
    Ptr4c vu = {{ attn_l + 2 * DD, attn_l + 3 * DD, attn_r + 0 * DD, attn_r + 1 * DD }};
    Ptr4m ou = {{ DU, DU + NU, DU + 2 * NU, DU + 3 * NU }};
    dot4_kernel<<<(NN / 4 * 64) / 256, 256, 0, stream>>>(feat_item, vi, oi, FBI, NI);
    dot4_kernel<<<(NN / 4 * 64) / 256, 256, 0, stream>>>(feat_user, vu, ou, FBU, NU);

    // ---- CSR build ----
    EdgeArgs ea;
    ea.src[0] = rel_u_src;      ea.dst[0] = rel_u_dst;
    ea.src[1] = rel_u_src + EE; ea.dst[1] = rel_u_dst + EE;
    ea.src[2] = rel_i_src;      ea.dst[2] = rel_i_dst;
    ea.src[3] = rel_i_src + EE; ea.dst[3] = rel_i_dst + EE;
    ea.src[4] = mp_u_src;       ea.dst[4] = mp_u_dst;
    ea.src[5] = mp_u_src + EE;  ea.dst[5] = mp_u_dst + EE;
    ea.src[6] = mp_i_src;       ea.dst[6] = mp_i_dst;
    ea.src[7] = mp_i_src + EE;  ea.dst[7] = mp_i_dst + EE;

    part1_kernel<<<8 * TPG, 256, 0, stream>>>(ea, CCNT, COARSE, DEG_SRC);
    scanb_kernel<<<8, 128, 0, stream>>>(CCNT, BKTBASE);

    WArgs wa;
    wa.el[0] = DI;      wa.er[0] = DU + 2 * NU;
    wa.el[1] = DI + NI; wa.er[1] = DU + 3 * NU;
    wa.el[2] = DU;      wa.er[2] = DI + 2 * NI;
    wa.el[3] = DU + NU; wa.er[3] = DI + 3 * NI;
    wa.deg_src = DEG_SRC;
    part2_kernel<<<8 * NBKT, 256, 0, stream>>>(CCNT, BKTBASE, COARSE, wa, BUCKET, ROW, DEGA, NIrm);

    // ---- fused aggregation (8 graphs, wave = node, packed weights) ----
    GatArgs ga;
    ga.fsrc[0] = FBI; ga.zout[0] = ZU;
    ga.fsrc[1] = FBI; ga.zout[1] = ZU + 64;
    ga.fsrc[2] = FBU; ga.zout[2] = ZI;
    ga.fsrc[3] = FBU; ga.zout[3] = ZI + 64;
    GcArgs gc;
    gc.feat[0] = FBU; gc.hout[0] = HU;
    gc.feat[1] = FBU; gc.hout[1] = HU + 64;
    gc.feat[2] = FBI; gc.hout[2] = HI;
    gc.feat[3] = FBI; gc.hout[3] = HI + 64;
    agg_kernel<<<8 * 12500, 256, 0, stream>>>(ga, gc, AGG, NIrm, DEGA, ROW, BUCKET);

    // ---- GC MFMA transform ----
    trans_kernel<<<4 * 782, 256, 0, stream>>>(gc, AGG, W16, b_gc);

    // ---- semantic attention (single launch, 4 instances, MFMA) ----
    SemArgs sa;
    sa.z[0] = ZU; sa.W1[0] = sa_rel_W1; sa.b1[0] = sa_rel_b1; sa.w2[0] = sa_rel_w2;
    sa.z[1] = ZI; sa.W1[1] = sa_rel_W1; sa.b1[1] = sa_rel_b1; sa.w2[1] = sa_rel_w2;
    sa.z[2] = HU; sa.W1[2] = sa_u_W1;   sa.b1[2] = sa_u_b1;   sa.w2[2] = sa_u_w2;
    sa.z[3] = HI; sa.W1[3] = sa_i_W1;   sa.b1[3] = sa_i_b1;   sa.w2[3] = sa_i_w2;
    sem_att_kernel<<<4 * 256, 256, 0, stream>>>(sa, WSUM);

    // ---- combine ----
    combine_kernel<<<((NU + NI) * 16 + 255) / 256, 256, 0, stream>>>(ZU, ZI, HU, HI, WSUM, (float*)d_out);
}